// Round 1
// baseline (512.051 us; speedup 1.0000x reference)
//
#include <hip/hip_runtime.h>
#include <hip/hip_bf16.h>

// ---- MoE top-2 fused FFN, bf16 MFMA path ------------------------------------
// Sizes fixed by the reference problem:
constexpr int D_    = 512;
constexpr int H_    = 1024;
constexpr int E_    = 8;
constexpr int NTOK_ = 16384;     // B*T = 8*2048
constexpr int MT_   = 32;        // tokens per FFN block tile
constexpr int NPAIR_= 2*NTOK_;   // top-2 pairs
constexpr float NEG_ = 0.01f;    // leaky relu slope

typedef short s16x8 __attribute__((ext_vector_type(8)));
typedef float f32x4 __attribute__((ext_vector_type(4)));

#define MFMA16(a,b,c) __builtin_amdgcn_mfma_f32_16x16x32_bf16((a),(b),(c),0,0,0)

__device__ __forceinline__ unsigned short f2bf(float f) {
  unsigned u = __float_as_uint(f);
  u += 0x7FFFu + ((u >> 16) & 1u);       // RNE
  return (unsigned short)(u >> 16);
}
__device__ __forceinline__ float bf2f(unsigned u16) {
  return __uint_as_float(u16 << 16);
}
__device__ __forceinline__ float leaky(float v) {
  return v > 0.f ? v : NEG_ * v;
}

// ---------------------------------------------------------------------------
// 1) Convert W1 [E,512,1024] and W2 [E,1024,512] fp32 -> bf16, laid out in
// MFMA B-fragment order: block (e, ntile, kstep) of 64 lanes x 8 bf16, where
// lane holds B[k = kstep*32 + (lane>>4)*8 + j][n = ntile*16 + (lane&15)].
// Main kernel then loads B frags as coalesced 16B/lane global loads.
__global__ __launch_bounds__(256) void convert_kernel(
    const float* __restrict__ W1, const float* __restrict__ W2,
    unsigned short* __restrict__ W1s, unsigned short* __restrict__ W2s) {
  int gid = blockIdx.x * 256 + threadIdx.x;
  const int HALF = E_ * 64 * 16 * 64;  // 524288 lane-chunks for W1
  if (gid < HALF) {
    int lane = gid & 63, kk = (gid >> 6) & 15, nt = (gid >> 10) & 63, e = gid >> 16;
    int k0 = kk * 32 + (lane >> 4) * 8;
    int n  = nt * 16 + (lane & 15);
    const float* src = W1 + ((size_t)(e * 512 + k0)) * 1024 + n;
    s16x8 v;
#pragma unroll
    for (int j = 0; j < 8; j++) v[j] = (short)f2bf(src[(size_t)j * 1024]);
    *(s16x8*)(W1s + (size_t)gid * 8) = v;
  } else {
    int c = gid - HALF;
    int lane = c & 63, kk = (c >> 6) & 31, nt = (c >> 11) & 31, e = c >> 16;
    int k0 = kk * 32 + (lane >> 4) * 8;
    int n  = nt * 16 + (lane & 15);
    const float* src = W2 + ((size_t)(e * 1024 + k0)) * 512 + n;
    s16x8 v;
#pragma unroll
    for (int j = 0; j < 8; j++) v[j] = (short)f2bf(src[(size_t)j * 512]);
    *(s16x8*)(W2s + (size_t)c * 8) = v;
  }
}

// ---------------------------------------------------------------------------
// 2) Router: one thread per token. Wr accesses are lane-uniform -> scalar
// loads. fp32 softmax + top-2 (strict > keeps lower index on ties, matching
// jax.lax.top_k). Atomic slot assignment per expert; prob sums for the loss.
__global__ __launch_bounds__(256) void router_kernel(
    const float* __restrict__ x, const float* __restrict__ Wr,
    const float* __restrict__ br,
    int* __restrict__ cnt, float* __restrict__ psum,
    int* __restrict__ tokE, int* __restrict__ tokSlot, float* __restrict__ tokW) {
  __shared__ float lp[E_];
  int tid = threadIdx.x;
  if (tid < E_) lp[tid] = 0.f;
  __syncthreads();

  int t = blockIdx.x * 256 + tid;
  float acc[E_];
#pragma unroll
  for (int e = 0; e < E_; e++) acc[e] = br[e];
  const float4* xr = (const float4*)(x + (size_t)t * D_);
  for (int i = 0; i < D_ / 4; i++) {
    float4 v = xr[i];
    const float* w = Wr + (size_t)i * 4 * E_;   // uniform across lanes
#pragma unroll
    for (int e = 0; e < E_; e++)
      acc[e] += v.x * w[e] + v.y * w[8 + e] + v.z * w[16 + e] + v.w * w[24 + e];
  }
  float mx = acc[0];
#pragma unroll
  for (int e = 1; e < E_; e++) mx = fmaxf(mx, acc[e]);
  float p[E_]; float s = 0.f;
#pragma unroll
  for (int e = 0; e < E_; e++) { p[e] = expf(acc[e] - mx); s += p[e]; }
  float inv = 1.f / s;
#pragma unroll
  for (int e = 0; e < E_; e++) { p[e] *= inv; atomicAdd(&lp[e], p[e]); }

  float m1 = -1.f, m2 = -1.f; int i1 = 0, i2 = 0;
#pragma unroll
  for (int e = 0; e < E_; e++) {
    float pe = p[e];
    if (pe > m1)      { m2 = m1; i2 = i1; m1 = pe; i1 = e; }
    else if (pe > m2) { m2 = pe; i2 = e; }
  }
  int s1 = atomicAdd(&cnt[i1], 1);
  int s2 = atomicAdd(&cnt[i2], 1);
  tokE[2 * t]     = i1; tokSlot[2 * t]     = s1; tokW[2 * t]     = m1;
  tokE[2 * t + 1] = i2; tokSlot[2 * t + 1] = s2; tokW[2 * t + 1] = m2;

  __syncthreads();
  if (tid < E_) atomicAdd(&psum[tid], lp[tid]);
}

// 3) Offsets (exclusive scan over 8 counts) + gating loss scalar.
__global__ void scan_kernel(const int* __restrict__ cnt, int* __restrict__ off,
                            const float* __restrict__ psum, float* __restrict__ loss_out) {
  if (threadIdx.x == 0) {
    int o = 0;
    for (int e = 0; e < E_; e++) { off[e] = o; o += cnt[e]; }
    float l = 0.f;
    for (int e = 0; e < E_; e++) {
      float d = 0.125f - psum[e] / (float)NTOK_;
      l += d * d;
    }
    *loss_out = (l / 8.f) * 1e-4f;
  }
}

// 4) pair -> compact position; also the reverse map for the FFN gather.
__global__ __launch_bounds__(256) void assign_kernel(
    const int* __restrict__ tokE, const int* __restrict__ tokSlot,
    const int* __restrict__ off,
    int* __restrict__ posOfTok, int* __restrict__ tokOfPos) {
  int p = blockIdx.x * 256 + threadIdx.x;
  if (p >= NPAIR_) return;
  int pos = off[tokE[p]] + tokSlot[p];
  posOfTok[p] = pos;
  tokOfPos[pos] = p >> 1;
}

// ---------------------------------------------------------------------------
// 5) Fused two-layer expert FFN. Block = (expert e, 32-token tile), 4 waves.
// GEMM1: h[32,1024] = leaky(x[32,512] @ W1_e + b1) computed in 8 chunks of
// 128 cols; each chunk round-trips through LDS (C-layout -> A-layout) and is
// immediately consumed by GEMM2: out[32,512] += h_chunk @ W2_e[chunk,:].
// Wave w owns h cols [w*32,+32) in GEMM1 and out cols [w*128,+128) in GEMM2.
__global__ __launch_bounds__(256) void ffn_kernel(
    const float* __restrict__ x,
    const unsigned short* __restrict__ W1s, const unsigned short* __restrict__ W2s,
    const float* __restrict__ b1, const float* __restrict__ b2,
    const int* __restrict__ cnt, const int* __restrict__ off,
    const int* __restrict__ tokOfPos, unsigned short* __restrict__ buf) {
  const int e = blockIdx.y;
  const int nTok = cnt[e];
  const int start = blockIdx.x * MT_;
  if (start >= nTok) return;
  const int valid = min(MT_, nTok - start);
  const int base = off[e] + start;

  __shared__ __align__(16) unsigned short xs[MT_][D_ + 8];   // +8 pad: bank stagger
  __shared__ __align__(16) unsigned short hs[MT_][128 + 8];
  __shared__ int toks[MT_];

  const int tid = threadIdx.x;
  const int wave = tid >> 6;
  const int lane = tid & 63;

  if (tid < MT_) toks[tid] = tokOfPos[base + min(tid, valid - 1)];
  __syncthreads();

  // stage x tile (fp32 -> bf16), coalesced 32B/lane per row
  for (int r = wave; r < MT_; r += 4) {
    const float4* src = (const float4*)(x + (size_t)toks[r] * D_);
    float4 a = src[lane * 2], b = src[lane * 2 + 1];
    s16x8 v;
    v[0] = (short)f2bf(a.x); v[1] = (short)f2bf(a.y);
    v[2] = (short)f2bf(a.z); v[3] = (short)f2bf(a.w);
    v[4] = (short)f2bf(b.x); v[5] = (short)f2bf(b.y);
    v[6] = (short)f2bf(b.z); v[7] = (short)f2bf(b.w);
    *(s16x8*)&xs[r][lane * 8] = v;
  }
  __syncthreads();

  const int qm = lane & 15;         // m (or n) within 16-tile
  const int qk = (lane >> 4) * 8;   // k offset within 32-K step
  const int qr = (lane >> 4) * 4;   // C/D row base

  f32x4 acc2[2][8];
#pragma unroll
  for (int mi = 0; mi < 2; mi++)
#pragma unroll
    for (int ni = 0; ni < 8; ni++) acc2[mi][ni] = {0.f, 0.f, 0.f, 0.f};

  for (int c = 0; c < 8; c++) {
    // ---- GEMM1 chunk: this wave computes h cols [c*128 + wave*32, +32)
    f32x4 acc1[2][2];
#pragma unroll
    for (int mi = 0; mi < 2; mi++)
#pragma unroll
      for (int ni = 0; ni < 2; ni++) acc1[mi][ni] = {0.f, 0.f, 0.f, 0.f};

    const unsigned short* B1base =
        W1s + ((size_t)(e * 64 + c * 8 + wave * 2) * 16) * 512 + lane * 8;
#pragma unroll 4
    for (int kk = 0; kk < 16; kk++) {
      s16x8 a0 = *(const s16x8*)&xs[qm][kk * 32 + qk];
      s16x8 a1 = *(const s16x8*)&xs[16 + qm][kk * 32 + qk];
      s16x8 b0 = *(const s16x8*)(B1base + (size_t)kk * 512);
      s16x8 b1f = *(const s16x8*)(B1base + (size_t)(16 + kk) * 512);
      acc1[0][0] = MFMA16(a0, b0, acc1[0][0]);
      acc1[1][0] = MFMA16(a1, b0, acc1[1][0]);
      acc1[0][1] = MFMA16(a0, b1f, acc1[0][1]);
      acc1[1][1] = MFMA16(a1, b1f, acc1[1][1]);
    }
    __syncthreads();  // previous chunk's hs reads are done
    // bias + leaky, C-layout -> row-major LDS (A-layout for GEMM2)
#pragma unroll
    for (int ni = 0; ni < 2; ni++) {
      int hcol = wave * 32 + ni * 16 + qm;
      float bb = b1[e * H_ + c * 128 + hcol];
#pragma unroll
      for (int mi = 0; mi < 2; mi++)
#pragma unroll
        for (int r4 = 0; r4 < 4; r4++)
          hs[mi * 16 + qr + r4][hcol] = f2bf(leaky(acc1[mi][ni][r4] + bb));
    }
    __syncthreads();
    // ---- GEMM2 partial: out[:, wave*128..+128) += h_chunk @ W2[c*128..+128, :]
    const unsigned short* B2base =
        W2s + ((size_t)((e * 32 + wave * 8) * 32 + c * 4)) * 512 + lane * 8;
#pragma unroll
    for (int kk = 0; kk < 4; kk++) {
      s16x8 a0 = *(const s16x8*)&hs[qm][kk * 32 + qk];
      s16x8 a1 = *(const s16x8*)&hs[16 + qm][kk * 32 + qk];
#pragma unroll
      for (int ni = 0; ni < 8; ni++) {
        s16x8 bb = *(const s16x8*)(B2base + ((size_t)ni * 32 + kk) * 512);
        acc2[0][ni] = MFMA16(a0, bb, acc2[0][ni]);
        acc2[1][ni] = MFMA16(a1, bb, acc2[1][ni]);
      }
    }
  }

  // epilogue: bias + leaky, store bf16 rows to compact buffer
#pragma unroll
  for (int mi = 0; mi < 2; mi++) {
#pragma unroll
    for (int r4 = 0; r4 < 4; r4++) {
      int row = mi * 16 + qr + r4;
      if (row < valid) {
        size_t rowbase = (size_t)(base + row) * D_;
#pragma unroll
        for (int ni = 0; ni < 8; ni++) {
          int col = wave * 128 + ni * 16 + qm;
          float v = leaky(acc2[mi][ni][r4] + b2[e * D_ + col]);
          buf[rowbase + col] = f2bf(v);
        }
      }
    }
  }
}

// 6) out[t] = w0*buf[pos0] + w1*buf[pos1]
__global__ __launch_bounds__(256) void combine_kernel(
    const unsigned short* __restrict__ buf, const int* __restrict__ posOfTok,
    const float* __restrict__ tokW, float* __restrict__ out) {
  int t = blockIdx.x;
  int tid = threadIdx.x;
  int p0 = posOfTok[2 * t], p1 = posOfTok[2 * t + 1];
  float w0 = tokW[2 * t], w1 = tokW[2 * t + 1];
  const unsigned* r0 = (const unsigned*)(buf + (size_t)p0 * D_);
  const unsigned* r1 = (const unsigned*)(buf + (size_t)p1 * D_);
  unsigned u0 = r0[tid], u1 = r1[tid];
  float2 o;
  o.x = w0 * bf2f(u0 & 0xFFFFu) + w1 * bf2f(u1 & 0xFFFFu);
  o.y = w0 * bf2f(u0 >> 16)     + w1 * bf2f(u1 >> 16);
  ((float2*)(out + (size_t)t * D_))[tid] = o;
}

// ---------------------------------------------------------------------------
extern "C" void kernel_launch(void* const* d_in, const int* in_sizes, int n_in,
                              void* d_out, int out_size, void* d_ws, size_t ws_size,
                              hipStream_t stream) {
  const float* x  = (const float*)d_in[0];
  const float* Wr = (const float*)d_in[1];
  const float* br = (const float*)d_in[2];
  const float* W1 = (const float*)d_in[3];
  const float* b1 = (const float*)d_in[4];
  const float* W2 = (const float*)d_in[5];
  const float* b2 = (const float*)d_in[6];
  float* out = (float*)d_out;

  // workspace layout (~68.2 MB total)
  char* ws = (char*)d_ws;
  int*   cnt      = (int*)(ws + 0);        // 8 ints   [zeroed]
  float* psum     = (float*)(ws + 64);     // 8 floats [zeroed]
  int*   off      = (int*)(ws + 128);      // 8 ints
  int*   tokE     = (int*)(ws + 4096);
  int*   tokSlot  = (int*)(ws + 4096 + 1 * 131072);
  float* tokW     = (float*)(ws + 4096 + 2 * 131072);
  int*   posOfTok = (int*)(ws + 4096 + 3 * 131072);
  int*   tokOfPos = (int*)(ws + 4096 + 4 * 131072);
  unsigned short* W1s = (unsigned short*)(ws + (1u << 20));              // 16 MB
  unsigned short* W2s = (unsigned short*)(ws + (1u << 20) + 16777216u);  // 16 MB
  unsigned short* buf = (unsigned short*)(ws + (1u << 20) + 33554432u);  // 32 MB

  hipMemsetAsync(d_ws, 0, 128, stream);
  convert_kernel<<<4096, 256, 0, stream>>>(W1, W2, W1s, W2s);
  router_kernel<<<NTOK_ / 256, 256, 0, stream>>>(x, Wr, br, cnt, psum,
                                                 tokE, tokSlot, tokW);
  scan_kernel<<<1, 64, 0, stream>>>(cnt, off, psum, out + (size_t)NTOK_ * D_);
  assign_kernel<<<NPAIR_ / 256, 256, 0, stream>>>(tokE, tokSlot, off,
                                                  posOfTok, tokOfPos);
  ffn_kernel<<<dim3(NTOK_ / MT_, E_), 256, 0, stream>>>(x, W1s, W2s, b1, b2,
                                                        cnt, off, tokOfPos, buf);
  combine_kernel<<<NTOK_, 256, 0, stream>>>(buf, posOfTok, tokW, out);
}

// Round 2
// 314.510 us; speedup vs baseline: 1.6281x; 1.6281x over previous
//
#include <hip/hip_runtime.h>
#include <hip/hip_bf16.h>

// ---- MoE top-2 fused FFN, bf16 MFMA path ------------------------------------
constexpr int D_    = 512;
constexpr int H_    = 1024;
constexpr int E_    = 8;
constexpr int NTOK_ = 16384;     // B*T = 8*2048
constexpr int MT_   = 64;        // tokens per FFN block tile
constexpr int NPAIR_= 2*NTOK_;   // top-2 pairs
constexpr float NEG_ = 0.01f;    // leaky relu slope

typedef short s16x8 __attribute__((ext_vector_type(8)));
typedef float f32x4 __attribute__((ext_vector_type(4)));

#define MFMA16(a,b,c) __builtin_amdgcn_mfma_f32_16x16x32_bf16((a),(b),(c),0,0,0)

__device__ __forceinline__ unsigned short f2bf(float f) {
  unsigned u = __float_as_uint(f);
  u += 0x7FFFu + ((u >> 16) & 1u);       // RNE
  return (unsigned short)(u >> 16);
}
__device__ __forceinline__ float bf2f(unsigned u16) {
  return __uint_as_float(u16 << 16);
}
__device__ __forceinline__ float leaky(float v) {
  return v > 0.f ? v : NEG_ * v;
}

// ---------------------------------------------------------------------------
// 1) Convert W1 [E,512,1024] and W2 [E,1024,512] fp32 -> bf16, in MFMA
// B-fragment order: block (e, ntile, kstep) of 64 lanes x 8 bf16; lane holds
// B[k = kstep*32 + (lane>>4)*8 + j][n = ntile*16 + (lane&15)].
__global__ __launch_bounds__(256) void convert_kernel(
    const float* __restrict__ W1, const float* __restrict__ W2,
    unsigned short* __restrict__ W1s, unsigned short* __restrict__ W2s) {
  int gid = blockIdx.x * 256 + threadIdx.x;
  const int HALF = E_ * 64 * 16 * 64;  // 524288 lane-chunks for W1
  if (gid < HALF) {
    int lane = gid & 63, kk = (gid >> 6) & 15, nt = (gid >> 10) & 63, e = gid >> 16;
    int k0 = kk * 32 + (lane >> 4) * 8;
    int n  = nt * 16 + (lane & 15);
    const float* src = W1 + ((size_t)(e * 512 + k0)) * 1024 + n;
    s16x8 v;
#pragma unroll
    for (int j = 0; j < 8; j++) v[j] = (short)f2bf(src[(size_t)j * 1024]);
    *(s16x8*)(W1s + (size_t)gid * 8) = v;
  } else {
    int c = gid - HALF;
    int lane = c & 63, kk = (c >> 6) & 31, nt = (c >> 11) & 31, e = c >> 16;
    int k0 = kk * 32 + (lane >> 4) * 8;
    int n  = nt * 16 + (lane & 15);
    const float* src = W2 + ((size_t)(e * 1024 + k0)) * 512 + n;
    s16x8 v;
#pragma unroll
    for (int j = 0; j < 8; j++) v[j] = (short)f2bf(src[(size_t)j * 512]);
    *(s16x8*)(W2s + (size_t)c * 8) = v;
  }
}

// ---------------------------------------------------------------------------
// 2) Router. Hierarchical slot assignment: per-block LDS counters, then ONE
// global atomic per expert per block (counters padded to 64B lines to avoid
// the same-line atomic serialization that cost ~300us in round 0).
__global__ __launch_bounds__(256) void router_kernel(
    const float* __restrict__ x, const float* __restrict__ Wr,
    const float* __restrict__ br,
    int* __restrict__ cnt, float* __restrict__ psum,
    int* __restrict__ tokE, int* __restrict__ tokSlot, float* __restrict__ tokW) {
  __shared__ int lcnt[E_];
  __shared__ int gbase[E_];
  __shared__ float lp[E_];
  int tid = threadIdx.x;
  if (tid < E_) { lcnt[tid] = 0; lp[tid] = 0.f; }
  __syncthreads();

  int t = blockIdx.x * 256 + tid;
  float acc[E_];
#pragma unroll
  for (int e = 0; e < E_; e++) acc[e] = br[e];
  const float4* xr = (const float4*)(x + (size_t)t * D_);
  for (int i = 0; i < D_ / 4; i++) {
    float4 v = xr[i];
    const float* w = Wr + (size_t)i * 4 * E_;   // uniform across lanes
#pragma unroll
    for (int e = 0; e < E_; e++)
      acc[e] += v.x * w[e] + v.y * w[8 + e] + v.z * w[16 + e] + v.w * w[24 + e];
  }
  float mx = acc[0];
#pragma unroll
  for (int e = 1; e < E_; e++) mx = fmaxf(mx, acc[e]);
  float p[E_]; float s = 0.f;
#pragma unroll
  for (int e = 0; e < E_; e++) { p[e] = expf(acc[e] - mx); s += p[e]; }
  float inv = 1.f / s;
#pragma unroll
  for (int e = 0; e < E_; e++) p[e] *= inv;

  // top-2 (strict > keeps lower index on ties, matching jax.lax.top_k)
  float m1 = -1.f, m2 = -1.f; int i1 = 0, i2 = 0;
#pragma unroll
  for (int e = 0; e < E_; e++) {
    float pe = p[e];
    if (pe > m1)      { m2 = m1; i2 = i1; m1 = pe; i1 = e; }
    else if (pe > m2) { m2 = pe; i2 = e; }
  }
  int s1 = atomicAdd(&lcnt[i1], 1);
  int s2 = atomicAdd(&lcnt[i2], 1);

  // wave-reduce router probs for the loss, then LDS accumulate
#pragma unroll
  for (int e = 0; e < E_; e++) {
    float v = p[e];
#pragma unroll
    for (int o = 32; o > 0; o >>= 1) v += __shfl_xor(v, o);
    if ((tid & 63) == 0) atomicAdd(&lp[e], v);
  }
  __syncthreads();
  if (tid < E_) {
    gbase[tid] = atomicAdd(&cnt[tid * 16], lcnt[tid]);   // stride-16: own line
    atomicAdd(&psum[tid * 16], lp[tid]);
  }
  __syncthreads();
  tokE[2 * t]     = i1; tokSlot[2 * t]     = gbase[i1] + s1; tokW[2 * t]     = m1;
  tokE[2 * t + 1] = i2; tokSlot[2 * t + 1] = gbase[i2] + s2; tokW[2 * t + 1] = m2;
}

// 3) Offsets + gating loss scalar.
__global__ void scan_kernel(const int* __restrict__ cnt, int* __restrict__ off,
                            const float* __restrict__ psum, float* __restrict__ loss_out) {
  if (threadIdx.x == 0) {
    int o = 0;
    for (int e = 0; e < E_; e++) { off[e] = o; o += cnt[e * 16]; }
    float l = 0.f;
    for (int e = 0; e < E_; e++) {
      float d = 0.125f - psum[e * 16] / (float)NTOK_;
      l += d * d;
    }
    *loss_out = (l / 8.f) * 1e-4f;
  }
}

// 4) pair -> compact position; reverse map for the FFN gather.
__global__ __launch_bounds__(256) void assign_kernel(
    const int* __restrict__ tokE, const int* __restrict__ tokSlot,
    const int* __restrict__ off,
    int* __restrict__ posOfTok, int* __restrict__ tokOfPos) {
  int p = blockIdx.x * 256 + threadIdx.x;
  if (p >= NPAIR_) return;
  int pos = off[tokE[p]] + tokSlot[p];
  posOfTok[p] = pos;
  tokOfPos[pos] = p >> 1;
}

// ---------------------------------------------------------------------------
// 5) Fused two-layer expert FFN. Block = (expert e = blockIdx%8 -> XCD-pinned
// so each expert's 2MB of weights stays hot in one XCD's 4MB L2) x 64-token
// tile, 8 waves. GEMM1: h[64,1024] in 8 chunks of 128 cols (wave owns 16);
// chunk round-trips through double-buffered LDS (1 barrier/chunk) and feeds
// GEMM2: out[64,512] += h_chunk @ W2[chunk,:] (wave owns 64 out cols).
__global__ __launch_bounds__(512, 2) void ffn_kernel(
    const float* __restrict__ x,
    const unsigned short* __restrict__ W1s, const unsigned short* __restrict__ W2s,
    const float* __restrict__ b1, const float* __restrict__ b2,
    const int* __restrict__ cnt, const int* __restrict__ off,
    const int* __restrict__ tokOfPos, unsigned short* __restrict__ buf) {
  const int e = blockIdx.x & 7;          // expert -> XCD affinity
  const int tile = blockIdx.x >> 3;
  const int nTok = cnt[e * 16];
  const int start = tile * MT_;
  if (start >= nTok) return;
  const int valid = min(MT_, nTok - start);
  const int base = off[e] + start;

  // 101.6 KB LDS (gfx950: 160 KB/WG) -> 1 block/CU, 8 waves resident
  __shared__ __align__(16) unsigned short xs[MT_][D_ + 8];     // 66.5 KB
  __shared__ __align__(16) unsigned short hs[2][MT_][136];     // 34.8 KB, dbuf
  __shared__ int toks[MT_];

  const int tid = threadIdx.x;
  const int w = tid >> 6;
  const int lane = tid & 63;

  if (tid < MT_) toks[tid] = tokOfPos[base + min(tid, valid - 1)];
  __syncthreads();

  // stage x tile (fp32 -> bf16), coalesced 32B/lane per row
  for (int r = w; r < MT_; r += 8) {
    const float4* src = (const float4*)(x + (size_t)toks[r] * D_);
    float4 a = src[lane * 2], b = src[lane * 2 + 1];
    s16x8 v;
    v[0] = (short)f2bf(a.x); v[1] = (short)f2bf(a.y);
    v[2] = (short)f2bf(a.z); v[3] = (short)f2bf(a.w);
    v[4] = (short)f2bf(b.x); v[5] = (short)f2bf(b.y);
    v[6] = (short)f2bf(b.z); v[7] = (short)f2bf(b.w);
    *(s16x8*)&xs[r][lane * 8] = v;
  }
  __syncthreads();

  const int qm = lane & 15;         // m (or n) within 16-tile
  const int qk = (lane >> 4) * 8;   // k offset within 32-K step
  const int qr = (lane >> 4) * 4;   // C/D row base

  f32x4 acc2[4][4];
#pragma unroll
  for (int mi = 0; mi < 4; mi++)
#pragma unroll
    for (int ni = 0; ni < 4; ni++) acc2[mi][ni] = {0.f, 0.f, 0.f, 0.f};

  for (int c = 0; c < 8; c++) {
    // ---- GEMM1 chunk: wave w computes h cols [c*128 + w*16, +16)
    f32x4 acc1[4];
#pragma unroll
    for (int mi = 0; mi < 4; mi++) acc1[mi] = {0.f, 0.f, 0.f, 0.f};

    const unsigned short* B1base =
        W1s + ((size_t)(e * 64 + c * 8 + w) * 16) * 512 + lane * 8;
#pragma unroll 4
    for (int kk = 0; kk < 16; kk++) {
      s16x8 b = *(const s16x8*)(B1base + (size_t)kk * 512);
#pragma unroll
      for (int mi = 0; mi < 4; mi++) {
        s16x8 a = *(const s16x8*)&xs[mi * 16 + qm][kk * 32 + qk];
        acc1[mi] = MFMA16(a, b, acc1[mi]);
      }
    }
    // bias + leaky, C-layout -> row-major LDS (A-layout for GEMM2)
    {
      int hcol = w * 16 + qm;
      float bb = b1[e * H_ + c * 128 + hcol];
#pragma unroll
      for (int mi = 0; mi < 4; mi++)
#pragma unroll
        for (int r4 = 0; r4 < 4; r4++)
          hs[c & 1][mi * 16 + qr + r4][hcol] = f2bf(leaky(acc1[mi][r4] + bb));
    }
    __syncthreads();   // hs[c&1] complete; dbuf makes this the only barrier
    // ---- GEMM2 partial: out[:, w*64..+64) += h_chunk @ W2[c*128..+128, :]
    const unsigned short* B2base =
        W2s + ((size_t)(e * 32) * 32) * 512 + lane * 8;
#pragma unroll
    for (int kk = 0; kk < 4; kk++) {
      s16x8 a[4];
#pragma unroll
      for (int mi = 0; mi < 4; mi++)
        a[mi] = *(const s16x8*)&hs[c & 1][mi * 16 + qm][kk * 32 + qk];
#pragma unroll
      for (int ni = 0; ni < 4; ni++) {
        s16x8 bb = *(const s16x8*)(B2base +
            (size_t)((w * 4 + ni) * 32 + c * 4 + kk) * 512);
#pragma unroll
        for (int mi = 0; mi < 4; mi++) acc2[mi][ni] = MFMA16(a[mi], bb, acc2[mi][ni]);
      }
    }
  }

  // epilogue: bias + leaky, store bf16 rows to compact buffer
#pragma unroll
  for (int mi = 0; mi < 4; mi++) {
#pragma unroll
    for (int r4 = 0; r4 < 4; r4++) {
      int row = mi * 16 + qr + r4;
      if (row < valid) {
        size_t rowbase = (size_t)(base + row) * D_;
#pragma unroll
        for (int ni = 0; ni < 4; ni++) {
          int col = w * 64 + ni * 16 + qm;
          float v = leaky(acc2[mi][ni][r4] + b2[e * D_ + col]);
          buf[rowbase + col] = f2bf(v);
        }
      }
    }
  }
}

// 6) out[t] = w0*buf[pos0] + w1*buf[pos1]
__global__ __launch_bounds__(256) void combine_kernel(
    const unsigned short* __restrict__ buf, const int* __restrict__ posOfTok,
    const float* __restrict__ tokW, float* __restrict__ out) {
  int t = blockIdx.x;
  int tid = threadIdx.x;
  int p0 = posOfTok[2 * t], p1 = posOfTok[2 * t + 1];
  float w0 = tokW[2 * t], w1 = tokW[2 * t + 1];
  const unsigned* r0 = (const unsigned*)(buf + (size_t)p0 * D_);
  const unsigned* r1 = (const unsigned*)(buf + (size_t)p1 * D_);
  unsigned u0 = r0[tid], u1 = r1[tid];
  float2 o;
  o.x = w0 * bf2f(u0 & 0xFFFFu) + w1 * bf2f(u1 & 0xFFFFu);
  o.y = w0 * bf2f(u0 >> 16)     + w1 * bf2f(u1 >> 16);
  ((float2*)(out + (size_t)t * D_))[tid] = o;
}

// ---------------------------------------------------------------------------
extern "C" void kernel_launch(void* const* d_in, const int* in_sizes, int n_in,
                              void* d_out, int out_size, void* d_ws, size_t ws_size,
                              hipStream_t stream) {
  const float* x  = (const float*)d_in[0];
  const float* Wr = (const float*)d_in[1];
  const float* br = (const float*)d_in[2];
  const float* W1 = (const float*)d_in[3];
  const float* b1 = (const float*)d_in[4];
  const float* W2 = (const float*)d_in[5];
  const float* b2 = (const float*)d_in[6];
  float* out = (float*)d_out;

  // workspace layout (~49.7 MB used)
  char* ws = (char*)d_ws;
  int*   cnt      = (int*)(ws + 0);        // 8 counters, stride 16 ints [zeroed]
  float* psum     = (float*)(ws + 512);    // 8 sums, stride 16 floats  [zeroed]
  int*   off      = (int*)(ws + 1024);     // 8 ints
  int*   tokE     = (int*)(ws + 4096);
  int*   tokSlot  = (int*)(ws + 4096 + 1 * 131072);
  float* tokW     = (float*)(ws + 4096 + 2 * 131072);
  int*   posOfTok = (int*)(ws + 4096 + 3 * 131072);
  int*   tokOfPos = (int*)(ws + 4096 + 4 * 131072);
  unsigned short* W1s = (unsigned short*)(ws + (1u << 20));              // 8 MB
  unsigned short* W2s = (unsigned short*)(ws + (1u << 20) + 16777216u);  // 8 MB
  unsigned short* buf = (unsigned short*)(ws + (1u << 20) + 33554432u);  // 32 MB

  hipMemsetAsync(d_ws, 0, 2048, stream);
  convert_kernel<<<4096, 256, 0, stream>>>(W1, W2, W1s, W2s);
  router_kernel<<<NTOK_ / 256, 256, 0, stream>>>(x, Wr, br, cnt, psum,
                                                 tokE, tokSlot, tokW);
  scan_kernel<<<1, 64, 0, stream>>>(cnt, off, psum, out + (size_t)NTOK_ * D_);
  assign_kernel<<<NPAIR_ / 256, 256, 0, stream>>>(tokE, tokSlot, off,
                                                  posOfTok, tokOfPos);
  // worst case: every token sends both picks wide -> 256 tiles/expert
  ffn_kernel<<<(NTOK_ / MT_) * E_, 512, 0, stream>>>(x, W1s, W2s, b1, b2,
                                                     cnt, off, tokOfPos, buf);
  combine_kernel<<<NTOK_, 256, 0, stream>>>(buf, posOfTok, tokW, out);
}

// Round 3
// 298.367 us; speedup vs baseline: 1.7162x; 1.0541x over previous
//
#include <hip/hip_runtime.h>
#include <hip/hip_bf16.h>

// ---- MoE top-2 fused FFN, bf16 MFMA path ------------------------------------
constexpr int D_    = 512;
constexpr int H_    = 1024;
constexpr int E_    = 8;
constexpr int NTOK_ = 16384;     // B*T = 8*2048
constexpr int MT_   = 64;        // tokens per FFN block tile
constexpr int NPAIR_= 2*NTOK_;   // top-2 pairs
constexpr float NEG_ = 0.01f;    // leaky relu slope

typedef short s16x8 __attribute__((ext_vector_type(8)));
typedef float f32x4 __attribute__((ext_vector_type(4)));

#define MFMA16(a,b,c) __builtin_amdgcn_mfma_f32_16x16x32_bf16((a),(b),(c),0,0,0)

__device__ __forceinline__ unsigned short f2bf(float f) {
  unsigned u = __float_as_uint(f);
  u += 0x7FFFu + ((u >> 16) & 1u);       // RNE
  return (unsigned short)(u >> 16);
}
__device__ __forceinline__ float bf2f(unsigned u16) {
  return __uint_as_float(u16 << 16);
}
__device__ __forceinline__ float leaky(float v) {
  return v > 0.f ? v : NEG_ * v;
}

// ---------------------------------------------------------------------------
// 1) prep = router (blocks 0..63, first so downstream deps clear early) +
// weight convert (blocks 64..4159). Convert lays W1/W2 out in MFMA B-fragment
// order: chunk (e, ntile, kstep) of 64 lanes x 8 bf16; lane holds
// B[k = kstep*32 + (lane>>4)*8 + j][n = ntile*16 + (lane&15)].
__global__ __launch_bounds__(256) void prep_kernel(
    const float* __restrict__ x, const float* __restrict__ Wr,
    const float* __restrict__ br,
    const float* __restrict__ W1, const float* __restrict__ W2,
    unsigned short* __restrict__ W1s, unsigned short* __restrict__ W2s,
    int* __restrict__ cnt, float* __restrict__ psum,
    int* __restrict__ tokE, int* __restrict__ tokSlot, float* __restrict__ tokW) {
  const int blk = blockIdx.x;
  const int tid = threadIdx.x;
  if (blk < 64) {
    // ---------------- router ----------------
    __shared__ int lcnt[E_];
    __shared__ int gbase[E_];
    __shared__ float lp[E_];
    if (tid < E_) { lcnt[tid] = 0; lp[tid] = 0.f; }
    __syncthreads();

    int t = blk * 256 + tid;
    float acc[E_];
#pragma unroll
    for (int e = 0; e < E_; e++) acc[e] = br[e];
    const float4* xr = (const float4*)(x + (size_t)t * D_);
    for (int i = 0; i < D_ / 4; i++) {
      float4 v = xr[i];
      const float* w = Wr + (size_t)i * 4 * E_;   // lane-uniform -> scalar loads
#pragma unroll
      for (int e = 0; e < E_; e++)
        acc[e] += v.x * w[e] + v.y * w[8 + e] + v.z * w[16 + e] + v.w * w[24 + e];
    }
    float mx = acc[0];
#pragma unroll
    for (int e = 1; e < E_; e++) mx = fmaxf(mx, acc[e]);
    float p[E_]; float s = 0.f;
#pragma unroll
    for (int e = 0; e < E_; e++) { p[e] = expf(acc[e] - mx); s += p[e]; }
    float inv = 1.f / s;
#pragma unroll
    for (int e = 0; e < E_; e++) p[e] *= inv;

    // top-2 (strict > keeps lower index on ties, matching jax.lax.top_k)
    float m1 = -1.f, m2 = -1.f; int i1 = 0, i2 = 0;
#pragma unroll
    for (int e = 0; e < E_; e++) {
      float pe = p[e];
      if (pe > m1)      { m2 = m1; i2 = i1; m1 = pe; i1 = e; }
      else if (pe > m2) { m2 = pe; i2 = e; }
    }
    int s1 = atomicAdd(&lcnt[i1], 1);
    int s2 = atomicAdd(&lcnt[i2], 1);

    // wave-reduce router probs for the loss, then LDS accumulate
#pragma unroll
    for (int e = 0; e < E_; e++) {
      float v = p[e];
#pragma unroll
      for (int o = 32; o > 0; o >>= 1) v += __shfl_xor(v, o);
      if ((tid & 63) == 0) atomicAdd(&lp[e], v);
    }
    __syncthreads();
    if (tid < E_) {
      gbase[tid] = atomicAdd(&cnt[tid * 16], lcnt[tid]);  // stride-16: own line
      atomicAdd(&psum[tid * 16], lp[tid]);
    }
    __syncthreads();
    tokE[2 * t]     = i1; tokSlot[2 * t]     = gbase[i1] + s1; tokW[2 * t]     = m1;
    tokE[2 * t + 1] = i2; tokSlot[2 * t + 1] = gbase[i2] + s2; tokW[2 * t + 1] = m2;
  } else {
    // ---------------- weight convert ----------------
    int gid = (blk - 64) * 256 + tid;
    const int HALF = E_ * 64 * 16 * 64;  // 524288 lane-chunks for W1
    if (gid < HALF) {
      int lane = gid & 63, kk = (gid >> 6) & 15, nt = (gid >> 10) & 63, e = gid >> 16;
      int k0 = kk * 32 + (lane >> 4) * 8;
      int n  = nt * 16 + (lane & 15);
      const float* src = W1 + ((size_t)(e * 512 + k0)) * 1024 + n;
      s16x8 v;
#pragma unroll
      for (int j = 0; j < 8; j++) v[j] = (short)f2bf(src[(size_t)j * 1024]);
      *(s16x8*)(W1s + (size_t)gid * 8) = v;
    } else {
      int c = gid - HALF;
      int lane = c & 63, kk = (c >> 6) & 31, nt = (c >> 11) & 31, e = c >> 16;
      int k0 = kk * 32 + (lane >> 4) * 8;
      int n  = nt * 16 + (lane & 15);
      const float* src = W2 + ((size_t)(e * 1024 + k0)) * 512 + n;
      s16x8 v;
#pragma unroll
      for (int j = 0; j < 8; j++) v[j] = (short)f2bf(src[(size_t)j * 512]);
      *(s16x8*)(W2s + (size_t)c * 8) = v;
    }
  }
}

// ---------------------------------------------------------------------------
// 2) assign: pair -> compact position (+ reverse map), offsets computed
// in-LDS from the padded counters; block 0 also writes the gating loss.
__global__ __launch_bounds__(256) void assign_kernel(
    const int* __restrict__ tokE, const int* __restrict__ tokSlot,
    const int* __restrict__ cnt, const float* __restrict__ psum,
    int* __restrict__ posOfTok, int* __restrict__ tokOfPos,
    float* __restrict__ loss_out) {
  __shared__ int soff[E_];
  int tid = threadIdx.x;
  if (tid == 0) {
    int o = 0;
#pragma unroll
    for (int e = 0; e < E_; e++) { soff[e] = o; o += cnt[e * 16]; }
  }
  __syncthreads();
  int p = blockIdx.x * 256 + tid;
  int pos = soff[tokE[p]] + tokSlot[p];
  posOfTok[p] = pos;
  tokOfPos[pos] = p >> 1;
  if (blockIdx.x == 0 && tid == 0) {
    float l = 0.f;
#pragma unroll
    for (int e = 0; e < E_; e++) {
      float d = 0.125f - psum[e * 16] / (float)NTOK_;
      l += d * d;
    }
    *loss_out = (l / 8.f) * 1e-4f;
  }
}

// ---------------------------------------------------------------------------
// 3) Fused two-layer expert FFN. Block = (expert e = blockIdx&7 -> XCD-pinned)
// x 64-token tile, 8 waves. H is processed in 2 chunks of 512 cols; wave owns
// 64 h-cols per chunk (acc1[4][4]) -> GEMM1 a-reads drop 4x vs round 2
// (the LDS read pipe was oversubscribed 1.5x vs the MFMA pipe). hs single
// buffer, 2 barriers/chunk, 5 barriers total.
__global__ __launch_bounds__(512, 2) void ffn_kernel(
    const float* __restrict__ x,
    const unsigned short* __restrict__ W1s, const unsigned short* __restrict__ W2s,
    const float* __restrict__ b1, const float* __restrict__ b2,
    const int* __restrict__ cnt, const int* __restrict__ tokOfPos,
    unsigned short* __restrict__ buf) {
  const int e = blockIdx.x & 7;          // expert -> XCD affinity
  const int tile = blockIdx.x >> 3;
  int nTok = 0, base0 = 0;
#pragma unroll
  for (int i = 0; i < E_; i++) {
    int ci = cnt[i * 16];
    if (i < e) base0 += ci;
    if (i == e) nTok = ci;
  }
  const int start = tile * MT_;
  if (start >= nTok) return;
  const int valid = min(MT_, nTok - start);
  const int base = base0 + start;

  // 130 KB LDS -> 1 block/CU, 8 waves resident
  __shared__ __align__(16) unsigned short xs[MT_][D_ + 8];   // 66.5 KB
  __shared__ __align__(16) unsigned short hs[MT_][D_ + 8];   // 66.5 KB

  const int tid = threadIdx.x;
  const int w = tid >> 6;
  const int lane = tid & 63;

  // stage x tile (fp32 -> bf16); token index is lane-uniform -> s_load
  for (int r = w; r < MT_; r += 8) {
    int tok = tokOfPos[base + min(r, valid - 1)];
    const float4* src = (const float4*)(x + (size_t)tok * D_);
    float4 a = src[lane * 2], b = src[lane * 2 + 1];
    s16x8 v;
    v[0] = (short)f2bf(a.x); v[1] = (short)f2bf(a.y);
    v[2] = (short)f2bf(a.z); v[3] = (short)f2bf(a.w);
    v[4] = (short)f2bf(b.x); v[5] = (short)f2bf(b.y);
    v[6] = (short)f2bf(b.z); v[7] = (short)f2bf(b.w);
    *(s16x8*)&xs[r][lane * 8] = v;
  }
  __syncthreads();

  const int qm = lane & 15;         // m (or n) within 16-tile
  const int qk = (lane >> 4) * 8;   // k offset within 32-K step
  const int qr = (lane >> 4) * 4;   // C/D row base

  f32x4 acc2[4][4];
#pragma unroll
  for (int mi = 0; mi < 4; mi++)
#pragma unroll
    for (int ni = 0; ni < 4; ni++) acc2[mi][ni] = {0.f, 0.f, 0.f, 0.f};

  // wave-constant B base pointers (lane*8 folded in)
  const unsigned short* B1w = W1s + ((size_t)(e * 64 + w * 4) * 16) * 512 + lane * 8;
  const unsigned short* B2w = W2s + ((size_t)(e * 32 + w * 4) * 32) * 512 + lane * 8;

  for (int c = 0; c < 2; c++) {
    // ---- GEMM1 chunk: wave w computes h cols [c*512 + w*64, +64)
    f32x4 acc1[4][4];
#pragma unroll
    for (int mi = 0; mi < 4; mi++)
#pragma unroll
      for (int ni = 0; ni < 4; ni++) acc1[mi][ni] = {0.f, 0.f, 0.f, 0.f};

    const unsigned short* B1c = B1w + (size_t)(c * 32 * 16) * 512;
#pragma unroll 4
    for (int kk = 0; kk < 16; kk++) {
      s16x8 bf[4], af[4];
#pragma unroll
      for (int ni = 0; ni < 4; ni++)
        bf[ni] = *(const s16x8*)(B1c + (size_t)(ni * 16 + kk) * 512);
#pragma unroll
      for (int mi = 0; mi < 4; mi++)
        af[mi] = *(const s16x8*)&xs[mi * 16 + qm][kk * 32 + qk];
#pragma unroll
      for (int ni = 0; ni < 4; ni++)
#pragma unroll
        for (int mi = 0; mi < 4; mi++)
          acc1[mi][ni] = MFMA16(af[mi], bf[ni], acc1[mi][ni]);
    }
    __syncthreads();   // prior chunk's hs fully consumed by all waves
    // bias + leaky, C-layout -> row-major LDS (A-layout for GEMM2)
#pragma unroll
    for (int ni = 0; ni < 4; ni++) {
      int hcol = w * 64 + ni * 16 + qm;
      float bb = b1[e * H_ + c * 512 + hcol];
#pragma unroll
      for (int mi = 0; mi < 4; mi++)
#pragma unroll
        for (int r4 = 0; r4 < 4; r4++)
          hs[mi * 16 + qr + r4][hcol] = f2bf(leaky(acc1[mi][ni][r4] + bb));
    }
    __syncthreads();   // hs ready
    // ---- GEMM2 partial: out[:, w*64..+64) += h_chunk @ W2[c*512..+512, :]
    const unsigned short* B2c = B2w + (size_t)(c * 16) * 512;
#pragma unroll 4
    for (int kk = 0; kk < 16; kk++) {
      s16x8 bf[4], af[4];
#pragma unroll
      for (int ni = 0; ni < 4; ni++)
        bf[ni] = *(const s16x8*)(B2c + (size_t)(ni * 32 + kk) * 512);
#pragma unroll
      for (int mi = 0; mi < 4; mi++)
        af[mi] = *(const s16x8*)&hs[mi * 16 + qm][kk * 32 + qk];
#pragma unroll
      for (int ni = 0; ni < 4; ni++)
#pragma unroll
        for (int mi = 0; mi < 4; mi++)
          acc2[mi][ni] = MFMA16(af[mi], bf[ni], acc2[mi][ni]);
    }
  }

  // epilogue: bias + leaky, store bf16 rows to compact buffer
#pragma unroll
  for (int mi = 0; mi < 4; mi++) {
#pragma unroll
    for (int r4 = 0; r4 < 4; r4++) {
      int row = mi * 16 + qr + r4;
      if (row < valid) {
        size_t rowbase = (size_t)(base + row) * D_;
#pragma unroll
        for (int ni = 0; ni < 4; ni++) {
          int col = w * 64 + ni * 16 + qm;
          float v = leaky(acc2[mi][ni][r4] + b2[e * D_ + col]);
          buf[rowbase + col] = f2bf(v);
        }
      }
    }
  }
}

// 4) out[t] = w0*buf[pos0] + w1*buf[pos1]; one wave per token, uint4 loads.
__global__ __launch_bounds__(256) void combine_kernel(
    const unsigned short* __restrict__ buf, const int* __restrict__ posOfTok,
    const float* __restrict__ tokW, float* __restrict__ out) {
  int t = blockIdx.x * 4 + (threadIdx.x >> 6);
  int lane = threadIdx.x & 63;
  int p0 = posOfTok[2 * t], p1 = posOfTok[2 * t + 1];   // lane-uniform
  float w0 = tokW[2 * t], w1 = tokW[2 * t + 1];
  uint4 u0 = ((const uint4*)(buf + (size_t)p0 * D_))[lane];
  uint4 u1 = ((const uint4*)(buf + (size_t)p1 * D_))[lane];
  float4 oA, oB;
  oA.x = w0 * bf2f(u0.x & 0xFFFFu) + w1 * bf2f(u1.x & 0xFFFFu);
  oA.y = w0 * bf2f(u0.x >> 16)     + w1 * bf2f(u1.x >> 16);
  oA.z = w0 * bf2f(u0.y & 0xFFFFu) + w1 * bf2f(u1.y & 0xFFFFu);
  oA.w = w0 * bf2f(u0.y >> 16)     + w1 * bf2f(u1.y >> 16);
  oB.x = w0 * bf2f(u0.z & 0xFFFFu) + w1 * bf2f(u1.z & 0xFFFFu);
  oB.y = w0 * bf2f(u0.z >> 16)     + w1 * bf2f(u1.z >> 16);
  oB.z = w0 * bf2f(u0.w & 0xFFFFu) + w1 * bf2f(u1.w & 0xFFFFu);
  oB.w = w0 * bf2f(u0.w >> 16)     + w1 * bf2f(u1.w >> 16);
  float4* dst = (float4*)(out + (size_t)t * D_);
  dst[lane * 2]     = oA;
  dst[lane * 2 + 1] = oB;
}

// ---------------------------------------------------------------------------
extern "C" void kernel_launch(void* const* d_in, const int* in_sizes, int n_in,
                              void* d_out, int out_size, void* d_ws, size_t ws_size,
                              hipStream_t stream) {
  const float* x  = (const float*)d_in[0];
  const float* Wr = (const float*)d_in[1];
  const float* br = (const float*)d_in[2];
  const float* W1 = (const float*)d_in[3];
  const float* b1 = (const float*)d_in[4];
  const float* W2 = (const float*)d_in[5];
  const float* b2 = (const float*)d_in[6];
  float* out = (float*)d_out;

  // workspace layout (~49.7 MB used)
  char* ws = (char*)d_ws;
  int*   cnt      = (int*)(ws + 0);        // 8 counters, stride 16 ints [zeroed]
  float* psum     = (float*)(ws + 512);    // 8 sums, stride 16 floats  [zeroed]
  int*   tokE     = (int*)(ws + 4096);
  int*   tokSlot  = (int*)(ws + 4096 + 1 * 131072);
  float* tokW     = (float*)(ws + 4096 + 2 * 131072);
  int*   posOfTok = (int*)(ws + 4096 + 3 * 131072);
  int*   tokOfPos = (int*)(ws + 4096 + 4 * 131072);
  unsigned short* W1s = (unsigned short*)(ws + (1u << 20));              // 8 MB
  unsigned short* W2s = (unsigned short*)(ws + (1u << 20) + 16777216u);  // 8 MB
  unsigned short* buf = (unsigned short*)(ws + (1u << 20) + 33554432u);  // 32 MB

  hipMemsetAsync(d_ws, 0, 2048, stream);
  prep_kernel<<<4160, 256, 0, stream>>>(x, Wr, br, W1, W2, W1s, W2s,
                                        cnt, psum, tokE, tokSlot, tokW);
  assign_kernel<<<NPAIR_ / 256, 256, 0, stream>>>(tokE, tokSlot, cnt, psum,
                                                  posOfTok, tokOfPos,
                                                  out + (size_t)NTOK_ * D_);
  // worst case: every token routes to one expert -> 256 tiles/expert
  ffn_kernel<<<(NTOK_ / MT_) * E_, 512, 0, stream>>>(x, W1s, W2s, b1, b2,
                                                     cnt, tokOfPos, buf);
  combine_kernel<<<NTOK_ / 4, 256, 0, stream>>>(buf, posOfTok, tokW, out);
}

// Round 4
// 295.093 us; speedup vs baseline: 1.7352x; 1.0111x over previous
//
#include <hip/hip_runtime.h>
#include <hip/hip_bf16.h>

// ---- MoE top-2 fused FFN, bf16 MFMA path ------------------------------------
constexpr int D_    = 512;
constexpr int H_    = 1024;
constexpr int E_    = 8;
constexpr int NTOK_ = 16384;     // B*T = 8*2048
constexpr int MT_   = 64;        // tokens per FFN block tile
constexpr int NPAIR_= 2*NTOK_;   // top-2 pairs
constexpr float NEG_ = 0.01f;    // leaky relu slope

typedef short s16x8 __attribute__((ext_vector_type(8)));
typedef float f32x4 __attribute__((ext_vector_type(4)));

#define MFMA16(a,b,c) __builtin_amdgcn_mfma_f32_16x16x32_bf16((a),(b),(c),0,0,0)

__device__ __forceinline__ unsigned short f2bf(float f) {
  unsigned u = __float_as_uint(f);
  u += 0x7FFFu + ((u >> 16) & 1u);       // RNE
  return (unsigned short)(u >> 16);
}
__device__ __forceinline__ float bf2f(unsigned u16) {
  return __uint_as_float(u16 << 16);
}
__device__ __forceinline__ float leaky(float v) {
  return v > 0.f ? v : NEG_ * v;
}

// ---------------------------------------------------------------------------
// 1) prep = router (blocks 0..63) + coalesced weight convert (2048 blocks).
// Convert v2: 64x64 fp32 tile -> LDS (coalesced 256B-segment reads, the v1
// 4KB-stride gather was ~60-100us) -> bf16 MFMA B-fragment chunks, written
// as coalesced 16B/lane stores. Fragment order: chunk (e, ntile, kstep):
// lane holds B[k = kstep*32 + (lane>>4)*8 + j][n = ntile*16 + (lane&15)].
__global__ __launch_bounds__(256) void prep_kernel(
    const float* __restrict__ x, const float* __restrict__ Wr,
    const float* __restrict__ br,
    const float* __restrict__ W1, const float* __restrict__ W2,
    unsigned short* __restrict__ W1s, unsigned short* __restrict__ W2s,
    int* __restrict__ cnt, float* __restrict__ psum,
    int* __restrict__ tokE, int* __restrict__ tokSlot, float* __restrict__ tokW) {
  const int blk = blockIdx.x;
  const int tid = threadIdx.x;
  if (blk < 64) {
    // ---------------- router ----------------
    __shared__ int lcnt[E_];
    __shared__ int gbase[E_];
    __shared__ float lp[E_];
    if (tid < E_) { lcnt[tid] = 0; lp[tid] = 0.f; }
    __syncthreads();

    int t = blk * 256 + tid;
    float acc[E_];
#pragma unroll
    for (int e = 0; e < E_; e++) acc[e] = br[e];
    const float4* xr = (const float4*)(x + (size_t)t * D_);
    for (int i = 0; i < D_ / 4; i++) {
      float4 v = xr[i];
      const float* w = Wr + (size_t)i * 4 * E_;   // lane-uniform -> scalar loads
#pragma unroll
      for (int e = 0; e < E_; e++)
        acc[e] += v.x * w[e] + v.y * w[8 + e] + v.z * w[16 + e] + v.w * w[24 + e];
    }
    float mx = acc[0];
#pragma unroll
    for (int e = 1; e < E_; e++) mx = fmaxf(mx, acc[e]);
    float p[E_]; float s = 0.f;
#pragma unroll
    for (int e = 0; e < E_; e++) { p[e] = expf(acc[e] - mx); s += p[e]; }
    float inv = 1.f / s;
#pragma unroll
    for (int e = 0; e < E_; e++) p[e] *= inv;

    // top-2 (strict > keeps lower index on ties, matching jax.lax.top_k)
    float m1 = -1.f, m2 = -1.f; int i1 = 0, i2 = 0;
#pragma unroll
    for (int e = 0; e < E_; e++) {
      float pe = p[e];
      if (pe > m1)      { m2 = m1; i2 = i1; m1 = pe; i1 = e; }
      else if (pe > m2) { m2 = pe; i2 = e; }
    }
    int s1 = atomicAdd(&lcnt[i1], 1);
    int s2 = atomicAdd(&lcnt[i2], 1);

#pragma unroll
    for (int e = 0; e < E_; e++) {
      float v = p[e];
#pragma unroll
      for (int o = 32; o > 0; o >>= 1) v += __shfl_xor(v, o);
      if ((tid & 63) == 0) atomicAdd(&lp[e], v);
    }
    __syncthreads();
    if (tid < E_) {
      gbase[tid] = atomicAdd(&cnt[tid * 16], lcnt[tid]);  // stride-16: own line
      atomicAdd(&psum[tid * 16], lp[tid]);
    }
    __syncthreads();
    tokE[2 * t]     = i1; tokSlot[2 * t]     = gbase[i1] + s1; tokW[2 * t]     = m1;
    tokE[2 * t + 1] = i2; tokSlot[2 * t + 1] = gbase[i2] + s2; tokW[2 * t + 1] = m2;
  } else {
    // ---------------- weight convert v2 (LDS transpose) ----------------
    __shared__ float ldsf[64][68];    // 64x64 tile, +4 pad
    int bid = blk - 64;               // 0..2047; <1024 -> W1, else W2
    const float* src;
    int e, kt, tc, srcStride;
    bool isW1 = bid < 1024;
    if (isW1) {
      e = bid >> 7; kt = (bid >> 4) & 7; tc = bid & 15; srcStride = 1024;
      src = W1 + ((size_t)(e * 512 + kt * 64)) * 1024 + tc * 64;
    } else {
      int b2 = bid - 1024;
      e = b2 >> 7; kt = (b2 >> 3) & 15; tc = b2 & 7; srcStride = 512;
      src = W2 + ((size_t)(e * 1024 + kt * 64)) * 512 + tc * 64;
    }
    // load 64x64 fp32 tile, coalesced: 16 lanes x float4 = 256B per row seg
#pragma unroll
    for (int rep = 0; rep < 4; rep++) {
      int row = rep * 16 + (tid >> 4);
      int c4  = (tid & 15) * 4;
      float4 v = *(const float4*)(src + (size_t)row * srcStride + c4);
      ldsf[row][c4] = v.x; ldsf[row][c4 + 1] = v.y;
      ldsf[row][c4 + 2] = v.z; ldsf[row][c4 + 3] = v.w;
    }
    __syncthreads();
    // write 8 fragment chunks (2 ksteps x 4 ntiles); 4 waves x 2 chunks
    int wv = tid >> 6, lane = tid & 63;
#pragma unroll
    for (int qi = 0; qi < 2; qi++) {
      int q = wv * 2 + qi;
      int ks = q >> 2, nt = q & 3;
      int k0 = ks * 32 + (lane >> 4) * 8;
      int n  = nt * 16 + (lane & 15);
      s16x8 v;
#pragma unroll
      for (int j = 0; j < 8; j++) v[j] = (short)f2bf(ldsf[k0 + j][n]);
      if (isW1) {
        int ntg = tc * 4 + nt, kkg = kt * 2 + ks;
        *(s16x8*)(W1s + (((size_t)e << 16) + (ntg << 10) + (kkg << 6) + lane) * 8) = v;
      } else {
        int ntg = tc * 4 + nt, kkg = kt * 2 + ks;
        *(s16x8*)(W2s + (((size_t)e << 16) + (ntg << 11) + (kkg << 6) + lane) * 8) = v;
      }
    }
  }
}

// ---------------------------------------------------------------------------
// 2) assign: pair -> compact position (+ reverse map); block 0 writes loss.
__global__ __launch_bounds__(256) void assign_kernel(
    const int* __restrict__ tokE, const int* __restrict__ tokSlot,
    const int* __restrict__ cnt, const float* __restrict__ psum,
    int* __restrict__ posOfTok, int* __restrict__ tokOfPos,
    float* __restrict__ loss_out) {
  __shared__ int soff[E_];
  int tid = threadIdx.x;
  if (tid == 0) {
    int o = 0;
#pragma unroll
    for (int e = 0; e < E_; e++) { soff[e] = o; o += cnt[e * 16]; }
  }
  __syncthreads();
  int p = blockIdx.x * 256 + tid;
  int pos = soff[tokE[p]] + tokSlot[p];
  posOfTok[p] = pos;
  tokOfPos[pos] = p >> 1;
  if (blockIdx.x == 0 && tid == 0) {
    float l = 0.f;
#pragma unroll
    for (int e = 0; e < E_; e++) {
      float d = 0.125f - psum[e * 16] / (float)NTOK_;
      l += d * d;
    }
    *loss_out = (l / 8.f) * 1e-4f;
  }
}

// ---------------------------------------------------------------------------
// 3) Fused two-layer expert FFN, r3 structure + explicit software pipelining:
// B-fragments prefetched 2 K-steps ahead (r3 was latency-bound: VGPR_Count=96
// showed the compiler kept <=2 kk of operands in flight, so every 16-MFMA
// group stalled ~200-600cyc on its 4 global B loads). GEMM2's first B-frags
// issue BEFORE the hs barrier so their latency hides under the barrier drain.
__global__ __launch_bounds__(512, 2) void ffn_kernel(
    const float* __restrict__ x,
    const unsigned short* __restrict__ W1s, const unsigned short* __restrict__ W2s,
    const float* __restrict__ b1, const float* __restrict__ b2,
    const int* __restrict__ cnt, const int* __restrict__ tokOfPos,
    unsigned short* __restrict__ buf) {
  const int e = blockIdx.x & 7;          // expert -> XCD affinity
  const int tile = blockIdx.x >> 3;
  int nTok = 0, base0 = 0;
#pragma unroll
  for (int i = 0; i < E_; i++) {
    int ci = cnt[i * 16];
    if (i < e) base0 += ci;
    if (i == e) nTok = ci;
  }
  const int start = tile * MT_;
  if (start >= nTok) return;
  const int valid = min(MT_, nTok - start);
  const int base = base0 + start;

  // 133 KB LDS -> 1 block/CU, 8 waves resident
  __shared__ __align__(16) unsigned short xs[MT_][D_ + 8];   // 66.5 KB
  __shared__ __align__(16) unsigned short hs[MT_][D_ + 8];   // 66.5 KB

  const int tid = threadIdx.x;
  const int w = tid >> 6;
  const int lane = tid & 63;

  // stage x tile (fp32 -> bf16); token index is lane-uniform -> s_load
  for (int r = w; r < MT_; r += 8) {
    int tok = tokOfPos[base + min(r, valid - 1)];
    const float4* src = (const float4*)(x + (size_t)tok * D_);
    float4 a = src[lane * 2], b = src[lane * 2 + 1];
    s16x8 v;
    v[0] = (short)f2bf(a.x); v[1] = (short)f2bf(a.y);
    v[2] = (short)f2bf(a.z); v[3] = (short)f2bf(a.w);
    v[4] = (short)f2bf(b.x); v[5] = (short)f2bf(b.y);
    v[6] = (short)f2bf(b.z); v[7] = (short)f2bf(b.w);
    *(s16x8*)&xs[r][lane * 8] = v;
  }
  __syncthreads();

  const int qm = lane & 15;         // m (or n) within 16-tile
  const int qk = (lane >> 4) * 8;   // k offset within 32-K step
  const int qr = (lane >> 4) * 4;   // C/D row base

  f32x4 acc2[4][4];
#pragma unroll
  for (int mi = 0; mi < 4; mi++)
#pragma unroll
    for (int ni = 0; ni < 4; ni++) acc2[mi][ni] = {0.f, 0.f, 0.f, 0.f};

  // wave-constant B base pointers (lane*8 folded in)
  const unsigned short* B1w = W1s + ((size_t)(e * 64 + w * 4) * 16) * 512 + lane * 8;
  const unsigned short* B2w = W2s + ((size_t)(e * 32 + w * 4) * 32) * 512 + lane * 8;

  for (int c = 0; c < 2; c++) {
    // ---- GEMM1 chunk: wave w computes h cols [c*512 + w*64, +64)
    f32x4 acc1[4][4];
#pragma unroll
    for (int mi = 0; mi < 4; mi++)
#pragma unroll
      for (int ni = 0; ni < 4; ni++) acc1[mi][ni] = {0.f, 0.f, 0.f, 0.f};

    const unsigned short* B1c = B1w + (size_t)(c * 32 * 16) * 512;
    float bb[4];
#pragma unroll
    for (int ni = 0; ni < 4; ni++)
      bb[ni] = b1[e * H_ + c * 512 + w * 64 + ni * 16 + qm];

    // 2-deep pipeline: slots hold kk and kk+1
    s16x8 bfp[2][4], afp[2][4];
#pragma unroll
    for (int s = 0; s < 2; s++) {
#pragma unroll
      for (int ni = 0; ni < 4; ni++)
        bfp[s][ni] = *(const s16x8*)(B1c + (size_t)(ni * 16 + s) * 512);
#pragma unroll
      for (int mi = 0; mi < 4; mi++)
        afp[s][mi] = *(const s16x8*)&xs[mi * 16 + qm][s * 32 + qk];
    }
#pragma unroll
    for (int kk = 0; kk < 16; kk++) {
      s16x8 bcur[4], acur[4];
#pragma unroll
      for (int ni = 0; ni < 4; ni++) bcur[ni] = bfp[kk & 1][ni];
#pragma unroll
      for (int mi = 0; mi < 4; mi++) acur[mi] = afp[kk & 1][mi];
      if (kk + 2 < 16) {   // refill freed slot BEFORE the MFMAs
#pragma unroll
        for (int ni = 0; ni < 4; ni++)
          bfp[kk & 1][ni] = *(const s16x8*)(B1c + (size_t)(ni * 16 + kk + 2) * 512);
#pragma unroll
        for (int mi = 0; mi < 4; mi++)
          afp[kk & 1][mi] = *(const s16x8*)&xs[mi * 16 + qm][(kk + 2) * 32 + qk];
      }
#pragma unroll
      for (int ni = 0; ni < 4; ni++)
#pragma unroll
        for (int mi = 0; mi < 4; mi++)
          acc1[mi][ni] = MFMA16(acur[mi], bcur[ni], acc1[mi][ni]);
    }
    __syncthreads();   // all waves done reading hs from previous chunk

    // GEMM2 B prefetch issued now -> latency hides under hs writes + barrier
    const unsigned short* B2c = B2w + (size_t)(c * 16) * 512;
    s16x8 b2p[2][4];
#pragma unroll
    for (int s = 0; s < 2; s++)
#pragma unroll
      for (int ni = 0; ni < 4; ni++)
        b2p[s][ni] = *(const s16x8*)(B2c + (size_t)(ni * 32 + s) * 512);

    // bias + leaky, C-layout -> row-major LDS (A-layout for GEMM2)
#pragma unroll
    for (int ni = 0; ni < 4; ni++) {
      int hcol = w * 64 + ni * 16 + qm;
#pragma unroll
      for (int mi = 0; mi < 4; mi++)
#pragma unroll
        for (int r4 = 0; r4 < 4; r4++)
          hs[mi * 16 + qr + r4][hcol] = f2bf(leaky(acc1[mi][ni][r4] + bb[ni]));
    }
    __syncthreads();   // hs ready

    // ---- GEMM2 partial: out[:, w*64..+64) += h_chunk @ W2[c*512..+512, :]
    s16x8 a2p[2][4];
#pragma unroll
    for (int s = 0; s < 2; s++)
#pragma unroll
      for (int mi = 0; mi < 4; mi++)
        a2p[s][mi] = *(const s16x8*)&hs[mi * 16 + qm][s * 32 + qk];
#pragma unroll
    for (int kk = 0; kk < 16; kk++) {
      s16x8 bcur[4], acur[4];
#pragma unroll
      for (int ni = 0; ni < 4; ni++) bcur[ni] = b2p[kk & 1][ni];
#pragma unroll
      for (int mi = 0; mi < 4; mi++) acur[mi] = a2p[kk & 1][mi];
      if (kk + 2 < 16) {
#pragma unroll
        for (int ni = 0; ni < 4; ni++)
          b2p[kk & 1][ni] = *(const s16x8*)(B2c + (size_t)(ni * 32 + kk + 2) * 512);
#pragma unroll
        for (int mi = 0; mi < 4; mi++)
          a2p[kk & 1][mi] = *(const s16x8*)&hs[mi * 16 + qm][(kk + 2) * 32 + qk];
      }
#pragma unroll
      for (int ni = 0; ni < 4; ni++)
#pragma unroll
        for (int mi = 0; mi < 4; mi++)
          acc2[mi][ni] = MFMA16(acur[mi], bcur[ni], acc2[mi][ni]);
    }
  }

  // epilogue: bias + leaky, store bf16 rows to compact buffer
#pragma unroll
  for (int mi = 0; mi < 4; mi++) {
#pragma unroll
    for (int r4 = 0; r4 < 4; r4++) {
      int row = mi * 16 + qr + r4;
      if (row < valid) {
        size_t rowbase = (size_t)(base + row) * D_;
#pragma unroll
        for (int ni = 0; ni < 4; ni++) {
          int col = w * 64 + ni * 16 + qm;
          float v = leaky(acc2[mi][ni][r4] + b2[e * D_ + col]);
          buf[rowbase + col] = f2bf(v);
        }
      }
    }
  }
}

// 4) out[t] = w0*buf[pos0] + w1*buf[pos1]; one wave per token, uint4 loads.
__global__ __launch_bounds__(256) void combine_kernel(
    const unsigned short* __restrict__ buf, const int* __restrict__ posOfTok,
    const float* __restrict__ tokW, float* __restrict__ out) {
  int t = blockIdx.x * 4 + (threadIdx.x >> 6);
  int lane = threadIdx.x & 63;
  int p0 = posOfTok[2 * t], p1 = posOfTok[2 * t + 1];   // lane-uniform
  float w0 = tokW[2 * t], w1 = tokW[2 * t + 1];
  uint4 u0 = ((const uint4*)(buf + (size_t)p0 * D_))[lane];
  uint4 u1 = ((const uint4*)(buf + (size_t)p1 * D_))[lane];
  float4 oA, oB;
  oA.x = w0 * bf2f(u0.x & 0xFFFFu) + w1 * bf2f(u1.x & 0xFFFFu);
  oA.y = w0 * bf2f(u0.x >> 16)     + w1 * bf2f(u1.x >> 16);
  oA.z = w0 * bf2f(u0.y & 0xFFFFu) + w1 * bf2f(u1.y & 0xFFFFu);
  oA.w = w0 * bf2f(u0.y >> 16)     + w1 * bf2f(u1.y >> 16);
  oB.x = w0 * bf2f(u0.z & 0xFFFFu) + w1 * bf2f(u1.z & 0xFFFFu);
  oB.y = w0 * bf2f(u0.z >> 16)     + w1 * bf2f(u1.z >> 16);
  oB.z = w0 * bf2f(u0.w & 0xFFFFu) + w1 * bf2f(u1.w & 0xFFFFu);
  oB.w = w0 * bf2f(u0.w >> 16)     + w1 * bf2f(u1.w >> 16);
  float4* dst = (float4*)(out + (size_t)t * D_);
  dst[lane * 2]     = oA;
  dst[lane * 2 + 1] = oB;
}

// ---------------------------------------------------------------------------
extern "C" void kernel_launch(void* const* d_in, const int* in_sizes, int n_in,
                              void* d_out, int out_size, void* d_ws, size_t ws_size,
                              hipStream_t stream) {
  const float* x  = (const float*)d_in[0];
  const float* Wr = (const float*)d_in[1];
  const float* br = (const float*)d_in[2];
  const float* W1 = (const float*)d_in[3];
  const float* b1 = (const float*)d_in[4];
  const float* W2 = (const float*)d_in[5];
  const float* b2 = (const float*)d_in[6];
  float* out = (float*)d_out;

  // workspace layout (~49.7 MB used)
  char* ws = (char*)d_ws;
  int*   cnt      = (int*)(ws + 0);        // 8 counters, stride 16 ints [zeroed]
  float* psum     = (float*)(ws + 512);    // 8 sums, stride 16 floats  [zeroed]
  int*   tokE     = (int*)(ws + 4096);
  int*   tokSlot  = (int*)(ws + 4096 + 1 * 131072);
  float* tokW     = (float*)(ws + 4096 + 2 * 131072);
  int*   posOfTok = (int*)(ws + 4096 + 3 * 131072);
  int*   tokOfPos = (int*)(ws + 4096 + 4 * 131072);
  unsigned short* W1s = (unsigned short*)(ws + (1u << 20));              // 8 MB
  unsigned short* W2s = (unsigned short*)(ws + (1u << 20) + 16777216u);  // 8 MB
  unsigned short* buf = (unsigned short*)(ws + (1u << 20) + 33554432u);  // 32 MB

  hipMemsetAsync(d_ws, 0, 2048, stream);
  prep_kernel<<<64 + 2048, 256, 0, stream>>>(x, Wr, br, W1, W2, W1s, W2s,
                                             cnt, psum, tokE, tokSlot, tokW);
  assign_kernel<<<NPAIR_ / 256, 256, 0, stream>>>(tokE, tokSlot, cnt, psum,
                                                  posOfTok, tokOfPos,
                                                  out + (size_t)NTOK_ * D_);
  // worst case: every token routes to one expert -> 256 tiles/expert
  ffn_kernel<<<(NTOK_ / MT_) * E_, 512, 0, stream>>>(x, W1s, W2s, b1, b2,
                                                     cnt, tokOfPos, buf);
  combine_kernel<<<NTOK_ / 4, 256, 0, stream>>>(buf, posOfTok, tokW, out);
}